// Round 1
// baseline (373.702 us; speedup 1.0000x reference)
//
#include <hip/hip_runtime.h>

#define NN 100000
#define NE 1600000
#define NSB 512
#define ESB (NE / NSB)   // 3125 edges per block
#define SCB 98           // scan blocks (1024 nodes each)

typedef __bf16 v8bf __attribute__((ext_vector_type(8)));
typedef float  v4f  __attribute__((ext_vector_type(4)));

union Frag { v8bf v; uint4 u; unsigned short s[8]; };

// fp32 -> bf16 (round-to-nearest-even), returns low 16 bits
__device__ inline unsigned f2bf(float f) {
    unsigned u = __float_as_uint(f);
    return (u + 0x7fffu + ((u >> 16) & 1u)) >> 16;
}

// accumulate 8 packed bf16 channels (uint4) into a[0..7]
#define ACC8(u) do { \
    a[0] += __uint_as_float((u).x << 16); \
    a[1] += __uint_as_float((u).x & 0xffff0000u); \
    a[2] += __uint_as_float((u).y << 16); \
    a[3] += __uint_as_float((u).y & 0xffff0000u); \
    a[4] += __uint_as_float((u).z << 16); \
    a[5] += __uint_as_float((u).z & 0xffff0000u); \
    a[6] += __uint_as_float((u).w << 16); \
    a[7] += __uint_as_float((u).w & 0xffff0000u); \
} while (0)

// broadcast lane j within 8-lane group: src = (lane & 0x18) | j
#define BCAST8(x, j) __builtin_amdgcn_ds_swizzle((x), 0x18 | ((j) << 5))

// ---------------- K1: degree count (global atomics) + weight pack ------------
__global__ void deg_wpack_kernel(const int* __restrict__ dst, int* __restrict__ deg,
                                 const float* __restrict__ W1, const float* __restrict__ W2,
                                 unsigned short* __restrict__ Wp1, unsigned short* __restrict__ Wp2) {
    int b = blockIdx.x, t = threadIdx.x;
    if (b < 2) {
        const float* W = b ? W2 : W1;
        unsigned short* Wp = b ? Wp2 : Wp1;
        for (int idx = t; idx < 4096; idx += 256) {
            int j = idx & 7;
            int n = (idx >> 3) & 15;
            int f = idx >> 7;          // 0..31
            int q = f & 3;
            int s = (f >> 2) & 1;
            int c = f >> 3;
            int k = 32 * s + 8 * q + j;
            Wp[idx] = (unsigned short)f2bf(W[k * 64 + (16 * c + n)]);
        }
    }
    int start = b * ESB, end = start + ESB;
    for (int e = start + t; e < end; e += 256)
        atomicAdd(&deg[dst[e]], 1);   // fire-and-forget, no return dependency
}

// ---------------- K2a: per-block sums of padded degree -----------------------
__global__ void scan_part_kernel(const int* __restrict__ deg, int* __restrict__ bsum) {
    __shared__ int sd[256];
    int b = blockIdx.x, t = threadIdx.x;
    int base = b * 1024 + t * 4;
    int s = 0;
    #pragma unroll
    for (int j = 0; j < 4; ++j)
        if (base + j < NN) s += (deg[base + j] + 7) & ~7;
    sd[t] = s;
    __syncthreads();
    #pragma unroll
    for (int off = 128; off; off >>= 1) {
        if (t < off) sd[t] += sd[t + off];
        __syncthreads();
    }
    if (t == 0) bsum[b] = sd[0];
}

// ---------------- K2b: exclusive scan of block sums --------------------------
__global__ void scan_base_kernel(int* __restrict__ bsum, int* __restrict__ row_start) {
    __shared__ int sd[128];
    int t = threadIdx.x;
    int v = (t < SCB) ? bsum[t] : 0;
    sd[t] = v;
    __syncthreads();
    #pragma unroll
    for (int off = 1; off < 128; off <<= 1) {
        int x = (t >= off) ? sd[t - off] : 0;
        __syncthreads();
        sd[t] += x;
        __syncthreads();
    }
    if (t < SCB) bsum[t] = sd[t] - v;      // exclusive base per block
    if (t == 127) row_start[NN] = sd[127]; // total padded edges
}

// ---------------- K2c: row_start / cursor / dinv + pad-fill ------------------
__global__ void scan_final_kernel(const int* __restrict__ deg, const int* __restrict__ bsum,
                                  int* __restrict__ row_start, int* __restrict__ cursor,
                                  float* __restrict__ dinv, int* __restrict__ srt) {
    __shared__ int sd[256];
    int b = blockIdx.x, t = threadIdx.x;
    int base = b * 1024 + t * 4;
    int d[4], p[4];
    int my = 0;
    #pragma unroll
    for (int j = 0; j < 4; ++j) {
        d[j] = (base + j < NN) ? deg[base + j] : 0;
        p[j] = (d[j] + 7) & ~7;
        my += p[j];
    }
    sd[t] = my;
    __syncthreads();
    #pragma unroll
    for (int off = 1; off < 256; off <<= 1) {
        int v = (t >= off) ? sd[t - off] : 0;
        __syncthreads();
        sd[t] += v;
        __syncthreads();
    }
    int rs = sd[t] - my + bsum[b];
    #pragma unroll
    for (int j = 0; j < 4; ++j) {
        if (base + j < NN) {
            row_start[base + j] = rs;
            cursor[base + j]    = rs;
            dinv[base + j]      = rsqrtf((float)(d[j] + 1));
            for (int k = d[j]; k < p[j]; ++k) srt[rs + k] = NN;  // pad -> zero row
            rs += p[j];
        }
    }
}

// ---------------- K3: atomic scatter into padded CSR -------------------------
__global__ void scatter_kernel(const int* __restrict__ src, const int* __restrict__ dst,
                               int* __restrict__ cursor, int* __restrict__ srt) {
    for (int e = blockIdx.x * 256 + threadIdx.x; e < NE; e += 2048 * 256) {
        int d = dst[e];
        int pos = atomicAdd(&cursor[d], 1);
        srt[pos] = src[e];
    }
}

// ---------------- gemm layer 1: fp32 input, bf16 output, MFMA ----------------
__global__ void gemm_mfma_f32_kernel(const float* __restrict__ in,
                                     const unsigned short* __restrict__ Wp,
                                     const float* __restrict__ dinv,
                                     unsigned* __restrict__ out) {
    int lane = threadIdx.x & 63;
    int wv = threadIdx.x >> 6;
    int node0 = blockIdx.x * 64 + wv * 16;
    int m = lane & 15, quad = lane >> 4;
    int node = node0 + m;
    int lnode = (node < NN) ? node : NN - 1;

    Frag a[2];
    const float* xr = in + lnode * 64 + quad * 8;
    #pragma unroll
    for (int s = 0; s < 2; ++s) {
        float4 f0 = *(const float4*)(xr + s * 32);
        float4 f1 = *(const float4*)(xr + s * 32 + 4);
        a[s].s[0] = (unsigned short)f2bf(f0.x);
        a[s].s[1] = (unsigned short)f2bf(f0.y);
        a[s].s[2] = (unsigned short)f2bf(f0.z);
        a[s].s[3] = (unsigned short)f2bf(f0.w);
        a[s].s[4] = (unsigned short)f2bf(f1.x);
        a[s].s[5] = (unsigned short)f2bf(f1.y);
        a[s].s[6] = (unsigned short)f2bf(f1.z);
        a[s].s[7] = (unsigned short)f2bf(f1.w);
    }
    Frag b[8];
    #pragma unroll
    for (int cs = 0; cs < 8; ++cs)
        b[cs].u = *(const uint4*)(Wp + ((cs * 4 + quad) * 16 + m) * 8);

    v4f acc[4] = {};
    #pragma unroll
    for (int c = 0; c < 4; ++c) {
        acc[c] = __builtin_amdgcn_mfma_f32_16x16x32_bf16(a[0].v, b[c * 2 + 0].v, acc[c], 0, 0, 0);
        acc[c] = __builtin_amdgcn_mfma_f32_16x16x32_bf16(a[1].v, b[c * 2 + 1].v, acc[c], 0, 0, 0);
    }
    #pragma unroll
    for (int r = 0; r < 4; ++r) {
        int onode = node0 + quad * 4 + r;
        float di = dinv[(onode < NN) ? onode : NN - 1];
        #pragma unroll
        for (int c = 0; c < 4; ++c) {
            float v = acc[c][r] * di;
            float p = __shfl_xor(v, 1);
            if (!(lane & 1)) {
                if (onode < NN)
                    out[onode * 32 + c * 8 + (m >> 1)] = f2bf(v) | (f2bf(p) << 16);
                else if (onode == NN)
                    out[onode * 32 + c * 8 + (m >> 1)] = 0u;   // zero row for padding
            }
        }
    }
}

// ---------------- shared gather core: 8 lanes/node, uint4 loads --------------
// Padded CSR: every list length is a multiple of 8; pads point at row NN (zeros).
__device__ inline void gather8(const int* __restrict__ row_start,
                               const int* __restrict__ srt,
                               const uint4* __restrict__ hb4,
                               int node, int q8, float a[8]) {
    int e = row_start[node];
    int end = row_start[node + 1];
    uint4 u0 = hb4[node * 8 + q8];   // self-loop term
    a[0] = __uint_as_float(u0.x << 16);
    a[1] = __uint_as_float(u0.x & 0xffff0000u);
    a[2] = __uint_as_float(u0.y << 16);
    a[3] = __uint_as_float(u0.y & 0xffff0000u);
    a[4] = __uint_as_float(u0.z << 16);
    a[5] = __uint_as_float(u0.z & 0xffff0000u);
    a[6] = __uint_as_float(u0.w << 16);
    a[7] = __uint_as_float(u0.w & 0xffff0000u);
    if (e >= end) return;
    int sidx = srt[e + q8];
    while (e < end) {
        int en = e + 8;
        int sn = 0;
        if (en < end) sn = srt[en + q8];          // prefetch next chunk's indices
        int s0 = BCAST8(sidx, 0);
        int s1 = BCAST8(sidx, 1);
        int s2 = BCAST8(sidx, 2);
        int s3 = BCAST8(sidx, 3);
        int s4 = BCAST8(sidx, 4);
        int s5 = BCAST8(sidx, 5);
        int s6 = BCAST8(sidx, 6);
        int s7 = BCAST8(sidx, 7);
        uint4 v0 = hb4[s0 * 8 + q8];
        uint4 v1 = hb4[s1 * 8 + q8];
        uint4 v2 = hb4[s2 * 8 + q8];
        uint4 v3 = hb4[s3 * 8 + q8];
        uint4 v4 = hb4[s4 * 8 + q8];
        uint4 v5 = hb4[s5 * 8 + q8];
        uint4 v6 = hb4[s6 * 8 + q8];
        uint4 v7 = hb4[s7 * 8 + q8];
        ACC8(v0); ACC8(v1); ACC8(v2); ACC8(v3);
        ACC8(v4); ACC8(v5); ACC8(v6); ACC8(v7);
        sidx = sn;
        e = en;
    }
}

// ---------------- F: layer-1 aggregate -> LDS -> layer-2 gemm (MFMA) ---------
__global__ void agg1_gemm2_kernel(const int* __restrict__ row_start,
                                  const int* __restrict__ srt,
                                  const uint4* __restrict__ hb4,   // bufA bf16 rows
                                  const float* __restrict__ dinv,
                                  const float* __restrict__ b1,
                                  const unsigned short* __restrict__ Wp2,
                                  unsigned* __restrict__ out /* bufC bf16 rows */) {
    __shared__ unsigned short hsl[64][80];   // 10240 B, 16B-aligned rows
    int t = threadIdx.x;
    int lane = t & 63, wv = t >> 6;
    int node0 = blockIdx.x * 64;
    int q8 = lane & 7, g = lane >> 3;
    float4 bb0 = *(const float4*)(b1 + q8 * 8);
    float4 bb1 = *(const float4*)(b1 + q8 * 8 + 4);

    #pragma unroll
    for (int pass = 0; pass < 2; ++pass) {
        int nl = wv * 16 + pass * 8 + g;
        int node = node0 + nl;
        int cn = (node < NN) ? node : NN - 1;
        float a[8];
        gather8(row_start, srt, hb4, cn, q8, a);
        float di = dinv[cn];
        a[0] = fmaxf(fmaf(di, a[0], bb0.x), 0.f);
        a[1] = fmaxf(fmaf(di, a[1], bb0.y), 0.f);
        a[2] = fmaxf(fmaf(di, a[2], bb0.z), 0.f);
        a[3] = fmaxf(fmaf(di, a[3], bb0.w), 0.f);
        a[4] = fmaxf(fmaf(di, a[4], bb1.x), 0.f);
        a[5] = fmaxf(fmaf(di, a[5], bb1.y), 0.f);
        a[6] = fmaxf(fmaf(di, a[6], bb1.z), 0.f);
        a[7] = fmaxf(fmaf(di, a[7], bb1.w), 0.f);
        uint4 pk;
        pk.x = f2bf(a[0]) | (f2bf(a[1]) << 16);
        pk.y = f2bf(a[2]) | (f2bf(a[3]) << 16);
        pk.z = f2bf(a[4]) | (f2bf(a[5]) << 16);
        pk.w = f2bf(a[6]) | (f2bf(a[7]) << 16);
        *(uint4*)&hsl[nl][q8 * 8] = pk;
    }
    __syncthreads();

    int m = lane & 15, quad = lane >> 4;
    Frag b[8];
    #pragma unroll
    for (int cs = 0; cs < 8; ++cs)
        b[cs].u = *(const uint4*)(Wp2 + ((cs * 4 + quad) * 16 + m) * 8);
    Frag a2[2];
    #pragma unroll
    for (int s = 0; s < 2; ++s)
        a2[s].u = *(const uint4*)&hsl[wv * 16 + m][s * 32 + quad * 8];

    v4f acc[4] = {};
    #pragma unroll
    for (int c = 0; c < 4; ++c) {
        acc[c] = __builtin_amdgcn_mfma_f32_16x16x32_bf16(a2[0].v, b[c * 2 + 0].v, acc[c], 0, 0, 0);
        acc[c] = __builtin_amdgcn_mfma_f32_16x16x32_bf16(a2[1].v, b[c * 2 + 1].v, acc[c], 0, 0, 0);
    }
    #pragma unroll
    for (int r = 0; r < 4; ++r) {
        int onode = node0 + wv * 16 + quad * 4 + r;
        float di = dinv[(onode < NN) ? onode : NN - 1];
        #pragma unroll
        for (int c = 0; c < 4; ++c) {
            float v = acc[c][r] * di;
            float p = __shfl_xor(v, 1);
            if (!(lane & 1)) {
                if (onode < NN)
                    out[onode * 32 + c * 8 + (m >> 1)] = f2bf(v) | (f2bf(p) << 16);
                else if (onode == NN)
                    out[onode * 32 + c * 8 + (m >> 1)] = 0u;   // zero row for padding
            }
        }
    }
}

// ---------------- G: layer-2 aggregate fused with FC + log_softmax -----------
__global__ void aggregate2_final_kernel(const int* __restrict__ row_start,
                                        const int* __restrict__ srt,
                                        const uint4* __restrict__ hb4,  // bufC
                                        const float* __restrict__ dinv,
                                        const float* __restrict__ b2,
                                        const float* __restrict__ Wfc,
                                        const float* __restrict__ bfc,
                                        float* __restrict__ out) {
    __shared__ float Ws[64][16];   // 4 KB
    __shared__ float hs[32][68];   // padded rows (272 B, 16-aligned)
    int t = threadIdx.x;
    #pragma unroll
    for (int k = 0; k < 4; ++k)
        ((float*)Ws)[k * 256 + t] = Wfc[k * 256 + t];

    int nl = t >> 3, q8 = t & 7;
    int node = blockIdx.x * 32 + nl;      // NN = 3125 * 32 exactly
    float a[8];
    gather8(row_start, srt, hb4, node, q8, a);
    float di = dinv[node];
    float4 bb0 = *(const float4*)(b2 + q8 * 8);
    float4 bb1 = *(const float4*)(b2 + q8 * 8 + 4);
    float4 r0, r1;
    r0.x = fmaxf(fmaf(di, a[0], bb0.x), 0.f);
    r0.y = fmaxf(fmaf(di, a[1], bb0.y), 0.f);
    r0.z = fmaxf(fmaf(di, a[2], bb0.z), 0.f);
    r0.w = fmaxf(fmaf(di, a[3], bb0.w), 0.f);
    r1.x = fmaxf(fmaf(di, a[4], bb1.x), 0.f);
    r1.y = fmaxf(fmaf(di, a[5], bb1.y), 0.f);
    r1.z = fmaxf(fmaf(di, a[6], bb1.z), 0.f);
    r1.w = fmaxf(fmaf(di, a[7], bb1.w), 0.f);
    *(float4*)&hs[nl][q8 * 8]     = r0;
    *(float4*)&hs[nl][q8 * 8 + 4] = r1;
    __syncthreads();

    #pragma unroll
    for (int it = 0; it < 2; ++it) {
        int idx = it * 256 + t;
        int n2 = idx >> 4;
        int c  = idx & 15;
        float acc = bfc[c];
        #pragma unroll
        for (int k = 0; k < 64; ++k)
            acc = fmaf(hs[n2][k], Ws[k][c], acc);
        float mx = acc;
        #pragma unroll
        for (int off = 8; off; off >>= 1)
            mx = fmaxf(mx, __shfl_xor(mx, off, 16));
        float ex = __expf(acc - mx);
        float s = ex;
        #pragma unroll
        for (int off = 8; off; off >>= 1)
            s += __shfl_xor(s, off, 16);
        out[blockIdx.x * 512 + idx] = acc - mx - __logf(s);
    }
}

extern "C" void kernel_launch(void* const* d_in, const int* in_sizes, int n_in,
                              void* d_out, int out_size, void* d_ws, size_t ws_size,
                              hipStream_t stream) {
    const float* x   = (const float*)d_in[0];
    const int*   ei  = (const int*)d_in[1];     // [2, E] int32
    const float* W1  = (const float*)d_in[2];
    const float* b1  = (const float*)d_in[3];
    const float* W2  = (const float*)d_in[4];
    const float* b2  = (const float*)d_in[5];
    const float* Wfc = (const float*)d_in[6];
    const float* bfc = (const float*)d_in[7];
    float* out = (float*)d_out;

    char* ws = (char*)d_ws;
    int*      deg        = (int*)(ws + 0);             // 400 KB
    float*    dinv       = (float*)(ws + 524288);      // 400 KB
    int*      row_start  = (int*)(ws + 1048576);       // (NN+1) ints
    int*      cursor     = (int*)(ws + 1572864);       // 400 KB
    int*      bsum       = (int*)(ws + 2097152);       // SCB ints
    int*      srt        = (int*)(ws + 4194304);       // padded CSR, <= 9.2 MB
    unsigned* bufA       = (unsigned*)(ws + 14000000); // (NN+1)*128 B bf16 rows
    unsigned* bufC       = (unsigned*)(ws + 27000000); // (NN+1)*128 B bf16 rows
    unsigned short* Wp1  = (unsigned short*)(ws + 40000000);  // 8 KB
    unsigned short* Wp2  = (unsigned short*)(ws + 40016384);  // 8 KB

    const int* src = ei;        // edge_index[0]
    const int* dst = ei + NE;   // edge_index[1]

    // ---- padded CSR build (atomic; order within a list is irrelevant) ----
    hipMemsetAsync(deg, 0, NN * sizeof(int), stream);
    deg_wpack_kernel<<<NSB, 256, 0, stream>>>(dst, deg, W1, W2, Wp1, Wp2);
    scan_part_kernel<<<SCB, 256, 0, stream>>>(deg, bsum);
    scan_base_kernel<<<1, 128, 0, stream>>>(bsum, row_start);
    scan_final_kernel<<<SCB, 256, 0, stream>>>(deg, bsum, row_start, cursor, dinv, srt);
    scatter_kernel<<<2048, 256, 0, stream>>>(src, dst, cursor, srt);

    // ---- layer 1 gemm (MFMA), also writes zero row NN ----
    gemm_mfma_f32_kernel<<<(NN + 63) / 64, 256, 0, stream>>>(x, Wp1, dinv, bufA);

    // ---- layer 1 aggregate + layer 2 gemm (fused) ----
    agg1_gemm2_kernel<<<(NN + 63) / 64, 256, 0, stream>>>(row_start, srt,
        (const uint4*)bufA, dinv, b1, Wp2, bufC);

    // ---- layer 2 aggregate + FC + log_softmax (fused) ----
    aggregate2_final_kernel<<<NN / 32, 256, 0, stream>>>(row_start, srt,
        (const uint4*)bufC, dinv, b2, Wfc, bfc, out);
}

// Round 2
// 211.990 us; speedup vs baseline: 1.7628x; 1.7628x over previous
//
#include <hip/hip_runtime.h>

#define NN 100000
#define NE 1600000
#define NPB 128                       // nodes per coarse bucket (node>>7)
#define NBUCK ((NN + NPB - 1) / NPB)  // 782
#define NSB 512                       // scatter blocks
#define ESB (NE / NSB)                // 3125 edges per scatter block
#define PCAP 3072                     // LDS staging cap in place_deg (bucket avg ~2046)
#define BPAD (NPB * 7)                // 896 pad-slack slots per bucket

typedef __bf16 v8bf __attribute__((ext_vector_type(8)));
typedef float  v4f  __attribute__((ext_vector_type(4)));

union Frag { v8bf v; uint4 u; unsigned short s[8]; };

// fp32 -> bf16 (round-to-nearest-even), returns low 16 bits
__device__ inline unsigned f2bf(float f) {
    unsigned u = __float_as_uint(f);
    return (u + 0x7fffu + ((u >> 16) & 1u)) >> 16;
}

// accumulate 8 packed bf16 channels (uint4) into a[0..7]
#define ACC8(u) do { \
    a[0] += __uint_as_float((u).x << 16); \
    a[1] += __uint_as_float((u).x & 0xffff0000u); \
    a[2] += __uint_as_float((u).y << 16); \
    a[3] += __uint_as_float((u).y & 0xffff0000u); \
    a[4] += __uint_as_float((u).z << 16); \
    a[5] += __uint_as_float((u).z & 0xffff0000u); \
    a[6] += __uint_as_float((u).w << 16); \
    a[7] += __uint_as_float((u).w & 0xffff0000u); \
} while (0)

// broadcast lane j within 8-lane group: src = (lane & 0x18) | j  (BitMode swizzle)
#define BCAST8(x, j) __builtin_amdgcn_ds_swizzle((x), 0x18 | ((j) << 5))

// ---------------- S0: per-block coarse bucket histogram ----------------
__global__ void hist_kernel(const int* __restrict__ dst, int* __restrict__ histT) {
    __shared__ int lhist[NBUCK];
    int t = threadIdx.x;
    for (int i = t; i < NBUCK; i += 256) lhist[i] = 0;
    __syncthreads();
    int start = blockIdx.x * ESB, end = start + ESB;
    for (int e = start + t; e < end; e += 256)
        atomicAdd(&lhist[dst[e] >> 7], 1);
    __syncthreads();
    for (int i = t; i < NBUCK; i += 256)
        histT[i * NSB + blockIdx.x] = lhist[i];   // transposed: bucket-major
}

// ---------------- S1: per-bucket scan of 512 block counts ----------------
__global__ void colscan_kernel(const int* __restrict__ histT, int* __restrict__ baseT,
                               int* __restrict__ btot) {
    __shared__ int sd[256];
    int k = blockIdx.x, t = threadIdx.x;
    const int* col = histT + k * NSB;
    int a0 = col[2 * t], a1 = col[2 * t + 1];
    int my = a0 + a1;
    sd[t] = my;
    __syncthreads();
    #pragma unroll
    for (int off = 1; off < 256; off <<= 1) {
        int v = (t >= off) ? sd[t - off] : 0;
        __syncthreads();
        sd[t] += v;
        __syncthreads();
    }
    int excl = sd[t] - my;
    baseT[k * NSB + 2 * t]     = excl;
    baseT[k * NSB + 2 * t + 1] = excl + a0;
    if (t == 255) btot[k] = sd[255];
}

// ---------------- S2: scan bucket totals -> bucket_start[NBUCK+1] ----------------
__global__ void bscan_kernel(const int* __restrict__ btot, int* __restrict__ bucket_start) {
    __shared__ int sd[256];
    int t = threadIdx.x;
    int base = t * 4;
    int d0 = (base + 0 < NBUCK) ? btot[base + 0] : 0;
    int d1 = (base + 1 < NBUCK) ? btot[base + 1] : 0;
    int d2 = (base + 2 < NBUCK) ? btot[base + 2] : 0;
    int d3 = (base + 3 < NBUCK) ? btot[base + 3] : 0;
    int my = d0 + d1 + d2 + d3;
    sd[t] = my;
    __syncthreads();
    #pragma unroll
    for (int off = 1; off < 256; off <<= 1) {
        int v = (t >= off) ? sd[t - off] : 0;
        __syncthreads();
        sd[t] += v;
        __syncthreads();
    }
    int excl = sd[t] - my;
    if (base + 0 < NBUCK) bucket_start[base + 0] = excl;
    if (base + 1 < NBUCK) bucket_start[base + 1] = excl + d0;
    if (base + 2 < NBUCK) bucket_start[base + 2] = excl + d0 + d1;
    if (base + 3 < NBUCK) bucket_start[base + 3] = excl + d0 + d1 + d2;
    if (t == 255) bucket_start[NBUCK] = sd[255];   // == NE
}

// ---------------- S3: stable bucket scatter, packed payload ----------------
// pack = (dst & 127) << 20 | src   (src < 2^20, loc < 2^7)
__global__ void scatter2_kernel(const int* __restrict__ src, const int* __restrict__ dst,
                                const int* __restrict__ baseT,
                                const int* __restrict__ bucket_start,
                                int* __restrict__ pairs) {
    __shared__ int lcur[NBUCK];
    int t = threadIdx.x, b = blockIdx.x;
    for (int i = t; i < NBUCK; i += 256)
        lcur[i] = bucket_start[i] + baseT[i * NSB + b];
    __syncthreads();
    int start = b * ESB, end = start + ESB;
    for (int e = start + t; e < end; e += 256) {
        int d = dst[e];
        int pos = atomicAdd(&lcur[d >> 7], 1);
        pairs[pos] = ((d & 127) << 20) | src[e];
    }
}

// ---------------- S4: per-bucket padded CSR placement + dinv -----------------
// Pads each node's list to a multiple of 8 (pad entries -> node NN = zero row).
// Padded region of bucket k starts at bucket_start[k] + BPAD*k.
// Emits rs_pd[node] = {row_start_padded, padded_deg}.
__global__ void place_deg_kernel(const int* __restrict__ bucket_start,
                                 const int* __restrict__ pairs,
                                 int2* __restrict__ rs_pd, float* __restrict__ dinv,
                                 int* __restrict__ srt) {
    __shared__ int lp[PCAP];
    __shared__ int lcnt[NPB];
    __shared__ int loff[NPB];
    __shared__ int lpos[NPB];
    __shared__ int sd[NPB];
    int k = blockIdx.x, t = threadIdx.x;
    int node0 = k * NPB;
    if (t < NPB) { lcnt[t] = 0; lpos[t] = 0; }
    __syncthreads();
    int bs = bucket_start[k], be = bucket_start[k + 1];
    int n = be - bs;
    int base = bs + k * BPAD;
    for (int pos = t; pos < n; pos += 256) {
        int p = pairs[bs + pos];
        if (pos < PCAP) lp[pos] = p;
        atomicAdd(&lcnt[p >> 20], 1);
    }
    __syncthreads();
    int my = (t < NPB) ? lcnt[t] : 0;
    int pd = (my + 7) & ~7;              // padded degree
    if (t < NPB) sd[t] = pd;
    __syncthreads();
    #pragma unroll
    for (int off = 1; off < NPB; off <<= 1) {
        int v = (t < NPB && t >= off) ? sd[t - off] : 0;
        __syncthreads();
        if (t < NPB) sd[t] += v;
        __syncthreads();
    }
    if (t < NPB) {
        int excl = sd[t] - pd;
        loff[t] = excl;
        int nd = node0 + t;
        if (nd < NN) {
            rs_pd[nd] = make_int2(base + excl, pd);
            dinv[nd] = rsqrtf((float)(my + 1));
            for (int kk = my; kk < pd; ++kk)
                srt[base + excl + kk] = NN;   // pad -> zero row
        }
    }
    __syncthreads();
    for (int pos = t; pos < n; pos += 256) {
        int p = (pos < PCAP) ? lp[pos] : pairs[bs + pos];
        int loc = p >> 20;
        int off = atomicAdd(&lpos[loc], 1);
        srt[base + loff[loc] + off] = p & 0xFFFFF;
    }
}

// ---------------- W pack: fp32 64x64 -> bf16 B-fragments ----------------
__global__ void wpack_kernel(const float* __restrict__ W1, const float* __restrict__ W2,
                             unsigned short* __restrict__ Wp1, unsigned short* __restrict__ Wp2) {
    const float* W = blockIdx.x ? W2 : W1;
    unsigned short* Wp = blockIdx.x ? Wp2 : Wp1;
    int t = threadIdx.x;
    for (int idx = t; idx < 4096; idx += 256) {
        int j = idx & 7;
        int n = (idx >> 3) & 15;
        int f = idx >> 7;          // 0..31
        int q = f & 3;
        int s = (f >> 2) & 1;
        int c = f >> 3;
        int kk = 32 * s + 8 * q + j;
        Wp[idx] = (unsigned short)f2bf(W[kk * 64 + (16 * c + n)]);
    }
}

// ---------------- gemm layer 1: fp32 input, bf16 output, MFMA ----------------
__global__ void gemm_mfma_f32_kernel(const float* __restrict__ in,
                                     const unsigned short* __restrict__ Wp,
                                     const float* __restrict__ dinv,
                                     unsigned* __restrict__ out) {
    int lane = threadIdx.x & 63;
    int wv = threadIdx.x >> 6;
    int node0 = blockIdx.x * 64 + wv * 16;
    int m = lane & 15, quad = lane >> 4;
    int node = node0 + m;
    int lnode = (node < NN) ? node : NN - 1;

    Frag a[2];
    const float* xr = in + lnode * 64 + quad * 8;
    #pragma unroll
    for (int s = 0; s < 2; ++s) {
        float4 f0 = *(const float4*)(xr + s * 32);
        float4 f1 = *(const float4*)(xr + s * 32 + 4);
        a[s].s[0] = (unsigned short)f2bf(f0.x);
        a[s].s[1] = (unsigned short)f2bf(f0.y);
        a[s].s[2] = (unsigned short)f2bf(f0.z);
        a[s].s[3] = (unsigned short)f2bf(f0.w);
        a[s].s[4] = (unsigned short)f2bf(f1.x);
        a[s].s[5] = (unsigned short)f2bf(f1.y);
        a[s].s[6] = (unsigned short)f2bf(f1.z);
        a[s].s[7] = (unsigned short)f2bf(f1.w);
    }
    Frag b[8];
    #pragma unroll
    for (int cs = 0; cs < 8; ++cs)
        b[cs].u = *(const uint4*)(Wp + ((cs * 4 + quad) * 16 + m) * 8);

    v4f acc[4] = {};
    #pragma unroll
    for (int c = 0; c < 4; ++c) {
        acc[c] = __builtin_amdgcn_mfma_f32_16x16x32_bf16(a[0].v, b[c * 2 + 0].v, acc[c], 0, 0, 0);
        acc[c] = __builtin_amdgcn_mfma_f32_16x16x32_bf16(a[1].v, b[c * 2 + 1].v, acc[c], 0, 0, 0);
    }
    #pragma unroll
    for (int r = 0; r < 4; ++r) {
        int onode = node0 + quad * 4 + r;
        float di = dinv[(onode < NN) ? onode : NN - 1];
        #pragma unroll
        for (int c = 0; c < 4; ++c) {
            float v = acc[c][r] * di;
            float p = __shfl_xor(v, 1);
            if (!(lane & 1)) {
                if (onode < NN)
                    out[onode * 32 + c * 8 + (m >> 1)] = f2bf(v) | (f2bf(p) << 16);
                else if (onode == NN)
                    out[onode * 32 + c * 8 + (m >> 1)] = 0u;   // zero row for padding
            }
        }
    }
}

// ---------------- shared gather core: 8 lanes/node, uint4 loads --------------
// Padded CSR: every list length is a multiple of 8; pads point at row NN (zeros).
__device__ inline void gather8(const int2* __restrict__ rs_pd,
                               const int* __restrict__ srt,
                               const uint4* __restrict__ hb4,
                               int node, int q8, float a[8]) {
    int2 rp = rs_pd[node];
    int e = rp.x;
    int end = rp.x + rp.y;
    uint4 u0 = hb4[node * 8 + q8];   // self-loop term
    a[0] = __uint_as_float(u0.x << 16);
    a[1] = __uint_as_float(u0.x & 0xffff0000u);
    a[2] = __uint_as_float(u0.y << 16);
    a[3] = __uint_as_float(u0.y & 0xffff0000u);
    a[4] = __uint_as_float(u0.z << 16);
    a[5] = __uint_as_float(u0.z & 0xffff0000u);
    a[6] = __uint_as_float(u0.w << 16);
    a[7] = __uint_as_float(u0.w & 0xffff0000u);
    if (e >= end) return;
    int sidx = srt[e + q8];
    while (e < end) {
        int en = e + 8;
        int sn = 0;
        if (en < end) sn = srt[en + q8];          // prefetch next chunk's indices
        int s0 = BCAST8(sidx, 0);
        int s1 = BCAST8(sidx, 1);
        int s2 = BCAST8(sidx, 2);
        int s3 = BCAST8(sidx, 3);
        int s4 = BCAST8(sidx, 4);
        int s5 = BCAST8(sidx, 5);
        int s6 = BCAST8(sidx, 6);
        int s7 = BCAST8(sidx, 7);
        uint4 v0 = hb4[s0 * 8 + q8];
        uint4 v1 = hb4[s1 * 8 + q8];
        uint4 v2 = hb4[s2 * 8 + q8];
        uint4 v3 = hb4[s3 * 8 + q8];
        uint4 v4 = hb4[s4 * 8 + q8];
        uint4 v5 = hb4[s5 * 8 + q8];
        uint4 v6 = hb4[s6 * 8 + q8];
        uint4 v7 = hb4[s7 * 8 + q8];
        ACC8(v0); ACC8(v1); ACC8(v2); ACC8(v3);
        ACC8(v4); ACC8(v5); ACC8(v6); ACC8(v7);
        sidx = sn;
        e = en;
    }
}

// ---------------- F: layer-1 aggregate -> LDS -> layer-2 gemm (MFMA) ---------
__global__ void agg1_gemm2_kernel(const int2* __restrict__ rs_pd,
                                  const int* __restrict__ srt,
                                  const uint4* __restrict__ hb4,   // bufA bf16 rows
                                  const float* __restrict__ dinv,
                                  const float* __restrict__ b1,
                                  const unsigned short* __restrict__ Wp2,
                                  unsigned* __restrict__ out /* bufC bf16 rows */) {
    __shared__ unsigned short hsl[64][80];   // 10240 B, 16B-aligned rows
    int t = threadIdx.x;
    int lane = t & 63, wv = t >> 6;
    int node0 = blockIdx.x * 64;
    int q8 = lane & 7, g = lane >> 3;
    float4 bb0 = *(const float4*)(b1 + q8 * 8);
    float4 bb1 = *(const float4*)(b1 + q8 * 8 + 4);

    #pragma unroll
    for (int pass = 0; pass < 2; ++pass) {
        int nl = wv * 16 + pass * 8 + g;
        int node = node0 + nl;
        int cn = (node < NN) ? node : NN - 1;
        float a[8];
        gather8(rs_pd, srt, hb4, cn, q8, a);
        float di = dinv[cn];
        a[0] = fmaxf(fmaf(di, a[0], bb0.x), 0.f);
        a[1] = fmaxf(fmaf(di, a[1], bb0.y), 0.f);
        a[2] = fmaxf(fmaf(di, a[2], bb0.z), 0.f);
        a[3] = fmaxf(fmaf(di, a[3], bb0.w), 0.f);
        a[4] = fmaxf(fmaf(di, a[4], bb1.x), 0.f);
        a[5] = fmaxf(fmaf(di, a[5], bb1.y), 0.f);
        a[6] = fmaxf(fmaf(di, a[6], bb1.z), 0.f);
        a[7] = fmaxf(fmaf(di, a[7], bb1.w), 0.f);
        uint4 pk;
        pk.x = f2bf(a[0]) | (f2bf(a[1]) << 16);
        pk.y = f2bf(a[2]) | (f2bf(a[3]) << 16);
        pk.z = f2bf(a[4]) | (f2bf(a[5]) << 16);
        pk.w = f2bf(a[6]) | (f2bf(a[7]) << 16);
        *(uint4*)&hsl[nl][q8 * 8] = pk;
    }
    __syncthreads();

    int m = lane & 15, quad = lane >> 4;
    Frag b[8];
    #pragma unroll
    for (int cs = 0; cs < 8; ++cs)
        b[cs].u = *(const uint4*)(Wp2 + ((cs * 4 + quad) * 16 + m) * 8);
    Frag a2[2];
    #pragma unroll
    for (int s = 0; s < 2; ++s)
        a2[s].u = *(const uint4*)&hsl[wv * 16 + m][s * 32 + quad * 8];

    v4f acc[4] = {};
    #pragma unroll
    for (int c = 0; c < 4; ++c) {
        acc[c] = __builtin_amdgcn_mfma_f32_16x16x32_bf16(a2[0].v, b[c * 2 + 0].v, acc[c], 0, 0, 0);
        acc[c] = __builtin_amdgcn_mfma_f32_16x16x32_bf16(a2[1].v, b[c * 2 + 1].v, acc[c], 0, 0, 0);
    }
    #pragma unroll
    for (int r = 0; r < 4; ++r) {
        int onode = node0 + wv * 16 + quad * 4 + r;
        float di = dinv[(onode < NN) ? onode : NN - 1];
        #pragma unroll
        for (int c = 0; c < 4; ++c) {
            float v = acc[c][r] * di;
            float p = __shfl_xor(v, 1);
            if (!(lane & 1)) {
                if (onode < NN)
                    out[onode * 32 + c * 8 + (m >> 1)] = f2bf(v) | (f2bf(p) << 16);
                else if (onode == NN)
                    out[onode * 32 + c * 8 + (m >> 1)] = 0u;   // zero row for padding
            }
        }
    }
}

// ---------------- G: layer-2 aggregate fused with FC + log_softmax -----------
__global__ void aggregate2_final_kernel(const int2* __restrict__ rs_pd,
                                        const int* __restrict__ srt,
                                        const uint4* __restrict__ hb4,  // bufC
                                        const float* __restrict__ dinv,
                                        const float* __restrict__ b2,
                                        const float* __restrict__ Wfc,
                                        const float* __restrict__ bfc,
                                        float* __restrict__ out) {
    __shared__ float Ws[64][16];   // 4 KB
    __shared__ float hs[32][68];   // padded rows
    int t = threadIdx.x;
    #pragma unroll
    for (int k = 0; k < 4; ++k)
        ((float*)Ws)[k * 256 + t] = Wfc[k * 256 + t];

    int nl = t >> 3, q8 = t & 7;
    int node = blockIdx.x * 32 + nl;      // NN = 3125 * 32 exactly
    float a[8];
    gather8(rs_pd, srt, hb4, node, q8, a);
    float di = dinv[node];
    float4 bb0 = *(const float4*)(b2 + q8 * 8);
    float4 bb1 = *(const float4*)(b2 + q8 * 8 + 4);
    float4 r0, r1;
    r0.x = fmaxf(fmaf(di, a[0], bb0.x), 0.f);
    r0.y = fmaxf(fmaf(di, a[1], bb0.y), 0.f);
    r0.z = fmaxf(fmaf(di, a[2], bb0.z), 0.f);
    r0.w = fmaxf(fmaf(di, a[3], bb0.w), 0.f);
    r1.x = fmaxf(fmaf(di, a[4], bb1.x), 0.f);
    r1.y = fmaxf(fmaf(di, a[5], bb1.y), 0.f);
    r1.z = fmaxf(fmaf(di, a[6], bb1.z), 0.f);
    r1.w = fmaxf(fmaf(di, a[7], bb1.w), 0.f);
    *(float4*)&hs[nl][q8 * 8]     = r0;
    *(float4*)&hs[nl][q8 * 8 + 4] = r1;
    __syncthreads();

    #pragma unroll
    for (int it = 0; it < 2; ++it) {
        int idx = it * 256 + t;
        int n2 = idx >> 4;
        int c  = idx & 15;
        float acc = bfc[c];
        #pragma unroll
        for (int k = 0; k < 64; ++k)
            acc = fmaf(hs[n2][k], Ws[k][c], acc);
        float mx = acc;
        #pragma unroll
        for (int off = 8; off; off >>= 1)
            mx = fmaxf(mx, __shfl_xor(mx, off, 16));
        float ex = __expf(acc - mx);
        float s = ex;
        #pragma unroll
        for (int off = 8; off; off >>= 1)
            s += __shfl_xor(s, off, 16);
        out[blockIdx.x * 512 + idx] = acc - mx - __logf(s);
    }
}

extern "C" void kernel_launch(void* const* d_in, const int* in_sizes, int n_in,
                              void* d_out, int out_size, void* d_ws, size_t ws_size,
                              hipStream_t stream) {
    const float* x   = (const float*)d_in[0];
    const int*   ei  = (const int*)d_in[1];     // [2, E] int32
    const float* W1  = (const float*)d_in[2];
    const float* b1  = (const float*)d_in[3];
    const float* W2  = (const float*)d_in[4];
    const float* b2  = (const float*)d_in[5];
    const float* Wfc = (const float*)d_in[6];
    const float* bfc = (const float*)d_in[7];
    float* out = (float*)d_out;

    char* ws = (char*)d_ws;
    int2*     rs_pd        = (int2*)(ws + 0);           //  800 KB (NN int2)
    float*    dinv         = (float*)(ws + 800000);     //  400 KB
    int*      btot         = (int*)(ws + 1200000);      //  3128 B
    int*      bucket_start = (int*)(ws + 1203200);      //  3132 B
    int*      histT        = (int*)(ws + 1206400);      //  1.6 MB -> ends 2807936
    int*      baseT        = (int*)(ws + 2807936);      //  1.6 MB -> ends 4409472
    int*      srt          = (int*)(ws + 4409472);      //  9.2 MB padded CSR -> ends 13612160
    unsigned* bufA         = (unsigned*)(ws + 13612160);// 12.8 MB bf16 rows -> ends 26412288
    int*      pairs        = (int*)(ws + 26412288);     //  6.4 MB (dead after place_deg)
    unsigned* bufC         = (unsigned*)(ws + 26412288);// 12.8 MB, overlays pairs -> ends 39212416
    unsigned short* Wp1    = (unsigned short*)(ws + 39212416);  // 8 KB
    unsigned short* Wp2    = (unsigned short*)(ws + 39228800);  // 8 KB (ends 39245184)

    const int* src = ei;        // edge_index[0]
    const int* dst = ei + NE;   // edge_index[1]

    // ---- weight pack (both layers) ----
    wpack_kernel<<<2, 256, 0, stream>>>(W1, W2, Wp1, Wp2);

    // ---- padded CSR build (deterministic two-level counting sort; LDS atomics only) ----
    hist_kernel<<<NSB, 256, 0, stream>>>(dst, histT);
    colscan_kernel<<<NBUCK, 256, 0, stream>>>(histT, baseT, btot);
    bscan_kernel<<<1, 256, 0, stream>>>(btot, bucket_start);
    scatter2_kernel<<<NSB, 256, 0, stream>>>(src, dst, baseT, bucket_start, pairs);
    place_deg_kernel<<<NBUCK, 256, 0, stream>>>(bucket_start, pairs, rs_pd, dinv, srt);

    // ---- layer 1 gemm (MFMA), also writes zero row NN ----
    gemm_mfma_f32_kernel<<<(NN + 63) / 64, 256, 0, stream>>>(x, Wp1, dinv, bufA);

    // ---- layer 1 aggregate + layer 2 gemm (fused) ----
    agg1_gemm2_kernel<<<(NN + 63) / 64, 256, 0, stream>>>(rs_pd, srt,
        (const uint4*)bufA, dinv, b1, Wp2, bufC);

    // ---- layer 2 aggregate + FC + log_softmax (fused) ----
    aggregate2_final_kernel<<<NN / 32, 256, 0, stream>>>(rs_pd, srt,
        (const uint4*)bufC, dinv, b2, Wfc, bfc, out);
}

// Round 4
// 207.488 us; speedup vs baseline: 1.8011x; 1.0217x over previous
//
#include <hip/hip_runtime.h>

#define NN 100000
#define NE 1600000
#define NPB 128                       // nodes per coarse bucket (node>>7)
#define NBUCK ((NN + NPB - 1) / NPB)  // 782
#define NSB 512                       // scatter blocks
#define ESB (NE / NSB)                // 3125 edges per scatter block
#define PCAP 3072                     // LDS staging cap in place_deg (bucket avg ~2046)
#define BPAD (NPB * 7)                // 896 pad-slack slots per bucket
#define GEMMB ((NN + 63) / 64)        // 1563 gemm blocks

typedef __bf16 v8bf __attribute__((ext_vector_type(8)));
typedef float  v4f  __attribute__((ext_vector_type(4)));

union Frag { v8bf v; uint4 u; unsigned short s[8]; };

// fp32 -> bf16 (round-to-nearest-even), returns low 16 bits
__device__ inline unsigned f2bf(float f) {
    unsigned u = __float_as_uint(f);
    return (u + 0x7fffu + ((u >> 16) & 1u)) >> 16;
}

// accumulate 8 packed bf16 channels (uint4) into a[0..7]
#define ACC8(u) do { \
    a[0] += __uint_as_float((u).x << 16); \
    a[1] += __uint_as_float((u).x & 0xffff0000u); \
    a[2] += __uint_as_float((u).y << 16); \
    a[3] += __uint_as_float((u).y & 0xffff0000u); \
    a[4] += __uint_as_float((u).z << 16); \
    a[5] += __uint_as_float((u).z & 0xffff0000u); \
    a[6] += __uint_as_float((u).w << 16); \
    a[7] += __uint_as_float((u).w & 0xffff0000u); \
} while (0)

// accumulate with per-edge scalar weight dj: a[c] += dj * unpack(u.c)
#define ACC8N(u, dj) do { \
    a[0] = fmaf((dj), __uint_as_float((u).x << 16),         a[0]); \
    a[1] = fmaf((dj), __uint_as_float((u).x & 0xffff0000u), a[1]); \
    a[2] = fmaf((dj), __uint_as_float((u).y << 16),         a[2]); \
    a[3] = fmaf((dj), __uint_as_float((u).y & 0xffff0000u), a[3]); \
    a[4] = fmaf((dj), __uint_as_float((u).z << 16),         a[4]); \
    a[5] = fmaf((dj), __uint_as_float((u).z & 0xffff0000u), a[5]); \
    a[6] = fmaf((dj), __uint_as_float((u).w << 16),         a[6]); \
    a[7] = fmaf((dj), __uint_as_float((u).w & 0xffff0000u), a[7]); \
} while (0)

// broadcast lane j within 8-lane group: src = (lane & 0x18) | j  (BitMode swizzle)
#define BCAST8(x, j) __builtin_amdgcn_ds_swizzle((x), 0x18 | ((j) << 5))

// ---------------- K1: per-block coarse bucket histogram + weight pack --------
__global__ void hist_wpack_kernel(const int* __restrict__ dst, int* __restrict__ histT,
                                  const float* __restrict__ W1, const float* __restrict__ W2,
                                  unsigned short* __restrict__ Wp1, unsigned short* __restrict__ Wp2) {
    __shared__ int lhist[NBUCK];
    int b = blockIdx.x, t = threadIdx.x;
    if (b >= NSB) {                    // 2 wpack blocks
        const float* W = (b - NSB) ? W2 : W1;
        unsigned short* Wp = (b - NSB) ? Wp2 : Wp1;
        for (int idx = t; idx < 4096; idx += 256) {
            int j = idx & 7;
            int n = (idx >> 3) & 15;
            int f = idx >> 7;          // 0..31
            int q = f & 3;
            int s = (f >> 2) & 1;
            int c = f >> 3;
            int kk = 32 * s + 8 * q + j;
            Wp[idx] = (unsigned short)f2bf(W[kk * 64 + (16 * c + n)]);
        }
        return;
    }
    for (int i = t; i < NBUCK; i += 256) lhist[i] = 0;
    __syncthreads();
    int start = b * ESB, end = start + ESB;
    for (int e = start + t; e < end; e += 256)
        atomicAdd(&lhist[dst[e] >> 7], 1);
    __syncthreads();
    for (int i = t; i < NBUCK; i += 256)
        histT[i * NSB + b] = lhist[i];   // transposed: bucket-major
}

// ---------------- K2: per-bucket scan of 512 block counts --------------------
__global__ void colscan_kernel(const int* __restrict__ histT, int* __restrict__ baseT,
                               int* __restrict__ btot) {
    __shared__ int sd[256];
    int k = blockIdx.x, t = threadIdx.x;
    const int* col = histT + k * NSB;
    int a0 = col[2 * t], a1 = col[2 * t + 1];
    int my = a0 + a1;
    sd[t] = my;
    __syncthreads();
    #pragma unroll
    for (int off = 1; off < 256; off <<= 1) {
        int v = (t >= off) ? sd[t - off] : 0;
        __syncthreads();
        sd[t] += v;
        __syncthreads();
    }
    int excl = sd[t] - my;
    baseT[k * NSB + 2 * t]     = excl;
    baseT[k * NSB + 2 * t + 1] = excl + a0;
    if (t == 255) btot[k] = sd[255];
}

// ---------------- K3: bucket scatter (local bucket_start scan) + gemm1 -------
// pack = (dst & 127) << 20 | src   (src < 2^20, loc < 2^7)
// Fat kernel: blocks [0,NSB) scatter; blocks [NSB, NSB+GEMMB) do layer-1 GEMM.
// bufA rows are UNSCALED h = x@W1 (bf16); row NN is zeroed for padding.
__global__ void scatter_gemm_kernel(const int* __restrict__ src, const int* __restrict__ dst,
                                    const int* __restrict__ baseT, const int* __restrict__ btot,
                                    int* __restrict__ pairs,
                                    const float* __restrict__ x,
                                    const unsigned short* __restrict__ Wp,
                                    unsigned* __restrict__ outA) {
    int b = blockIdx.x, t = threadIdx.x;
    if (b < NSB) {
        __shared__ int lcur[NBUCK];
        __shared__ int sd[256];
        // local exclusive scan of btot -> bucket_start, fused with baseT add
        int base4 = t * 4;
        int d0 = (base4 + 0 < NBUCK) ? btot[base4 + 0] : 0;
        int d1 = (base4 + 1 < NBUCK) ? btot[base4 + 1] : 0;
        int d2 = (base4 + 2 < NBUCK) ? btot[base4 + 2] : 0;
        int d3 = (base4 + 3 < NBUCK) ? btot[base4 + 3] : 0;
        int my = d0 + d1 + d2 + d3;
        sd[t] = my;
        __syncthreads();
        #pragma unroll
        for (int off = 1; off < 256; off <<= 1) {
            int v = (t >= off) ? sd[t - off] : 0;
            __syncthreads();
            sd[t] += v;
            __syncthreads();
        }
        int excl = sd[t] - my;
        if (base4 + 0 < NBUCK) lcur[base4 + 0] = excl + baseT[(base4 + 0) * NSB + b];
        if (base4 + 1 < NBUCK) lcur[base4 + 1] = excl + d0 + baseT[(base4 + 1) * NSB + b];
        if (base4 + 2 < NBUCK) lcur[base4 + 2] = excl + d0 + d1 + baseT[(base4 + 2) * NSB + b];
        if (base4 + 3 < NBUCK) lcur[base4 + 3] = excl + d0 + d1 + d2 + baseT[(base4 + 3) * NSB + b];
        __syncthreads();
        int start = b * ESB, end = start + ESB;
        for (int e = start + t; e < end; e += 256) {
            int d = dst[e];
            int pos = atomicAdd(&lcur[d >> 7], 1);
            pairs[pos] = ((d & 127) << 20) | src[e];
        }
        return;
    }
    // ---- gemm1: fp32 input, bf16 unscaled output ----
    int lane = t & 63;
    int wv = t >> 6;
    int node0 = (b - NSB) * 64 + wv * 16;
    int m = lane & 15, quad = lane >> 4;
    int node = node0 + m;
    int lnode = (node < NN) ? node : NN - 1;

    Frag a[2];
    const float* xr = x + lnode * 64 + quad * 8;
    #pragma unroll
    for (int s = 0; s < 2; ++s) {
        float4 f0 = *(const float4*)(xr + s * 32);
        float4 f1 = *(const float4*)(xr + s * 32 + 4);
        a[s].s[0] = (unsigned short)f2bf(f0.x);
        a[s].s[1] = (unsigned short)f2bf(f0.y);
        a[s].s[2] = (unsigned short)f2bf(f0.z);
        a[s].s[3] = (unsigned short)f2bf(f0.w);
        a[s].s[4] = (unsigned short)f2bf(f1.x);
        a[s].s[5] = (unsigned short)f2bf(f1.y);
        a[s].s[6] = (unsigned short)f2bf(f1.z);
        a[s].s[7] = (unsigned short)f2bf(f1.w);
    }
    Frag bf[8];
    #pragma unroll
    for (int cs = 0; cs < 8; ++cs)
        bf[cs].u = *(const uint4*)(Wp + ((cs * 4 + quad) * 16 + m) * 8);

    v4f acc[4] = {};
    #pragma unroll
    for (int c = 0; c < 4; ++c) {
        acc[c] = __builtin_amdgcn_mfma_f32_16x16x32_bf16(a[0].v, bf[c * 2 + 0].v, acc[c], 0, 0, 0);
        acc[c] = __builtin_amdgcn_mfma_f32_16x16x32_bf16(a[1].v, bf[c * 2 + 1].v, acc[c], 0, 0, 0);
    }
    #pragma unroll
    for (int r = 0; r < 4; ++r) {
        int onode = node0 + quad * 4 + r;
        #pragma unroll
        for (int c = 0; c < 4; ++c) {
            float v = acc[c][r];
            float p = __shfl_xor(v, 1);
            if (!(lane & 1)) {
                if (onode < NN)
                    outA[onode * 32 + c * 8 + (m >> 1)] = f2bf(v) | (f2bf(p) << 16);
                else if (onode == NN)
                    outA[onode * 32 + c * 8 + (m >> 1)] = 0u;   // zero row for padding
            }
        }
    }
}

// ---------------- K4: per-bucket padded CSR placement + dinv -----------------
// Pads each node's list to a multiple of 8 (pad entries -> node NN = zero row).
// bucket_start derived locally: bs = sum(btot[0..k-1]); srt base = bs + BPAD*k.
__global__ void place_deg_kernel(const int* __restrict__ btot,
                                 const int* __restrict__ pairs,
                                 int2* __restrict__ rs_pd, float* __restrict__ dinv,
                                 int* __restrict__ srt) {
    __shared__ int lp[PCAP];
    __shared__ int lcnt[NPB];
    __shared__ int loff[NPB];
    __shared__ int lpos[NPB];
    __shared__ int sd[256];
    __shared__ int bs_s;
    int k = blockIdx.x, t = threadIdx.x;
    int node0 = k * NPB;
    // bs = prefix sum of btot[0..k)
    int part = 0;
    for (int i = t; i < k; i += 256) part += btot[i];
    sd[t] = part;
    __syncthreads();
    #pragma unroll
    for (int off = 128; off; off >>= 1) {
        if (t < off) sd[t] += sd[t + off];
        __syncthreads();
    }
    if (t == 0) bs_s = sd[0];
    if (t < NPB) { lcnt[t] = 0; lpos[t] = 0; }
    if (k == 0 && t == 0) dinv[NN] = 0.f;   // dinv of the zero row (pads)
    __syncthreads();
    int bs = bs_s;
    int n = btot[k];
    int base = bs + k * BPAD;
    for (int pos = t; pos < n; pos += 256) {
        int p = pairs[bs + pos];
        if (pos < PCAP) lp[pos] = p;
        atomicAdd(&lcnt[p >> 20], 1);
    }
    __syncthreads();
    int my = (t < NPB) ? lcnt[t] : 0;
    int pd = (my + 7) & ~7;              // padded degree
    if (t < NPB) sd[t] = pd;
    __syncthreads();
    #pragma unroll
    for (int off = 1; off < NPB; off <<= 1) {
        int v = (t < NPB && t >= off) ? sd[t - off] : 0;
        __syncthreads();
        if (t < NPB) sd[t] += v;
        __syncthreads();
    }
    if (t < NPB) {
        int excl = sd[t] - pd;
        loff[t] = excl;
        int nd = node0 + t;
        if (nd < NN) {
            rs_pd[nd] = make_int2(base + excl, pd);
            dinv[nd] = rsqrtf((float)(my + 1));
            for (int kk = my; kk < pd; ++kk)
                srt[base + excl + kk] = NN;   // pad -> zero row
        }
    }
    __syncthreads();
    for (int pos = t; pos < n; pos += 256) {
        int p = (pos < PCAP) ? lp[pos] : pairs[bs + pos];
        int loc = p >> 20;
        int off = atomicAdd(&lpos[loc], 1);
        srt[base + loff[loc] + off] = p & 0xFFFFF;
    }
}

// ---------------- gather core A: prescaled rows (layer 2) --------------------
__device__ inline void gather8(const int2* __restrict__ rs_pd,
                               const int* __restrict__ srt,
                               const uint4* __restrict__ hb4,
                               int node, int q8, float a[8]) {
    int2 rp = rs_pd[node];
    int e = rp.x;
    int end = rp.x + rp.y;
    uint4 u0 = hb4[node * 8 + q8];   // self-loop term
    a[0] = __uint_as_float(u0.x << 16);
    a[1] = __uint_as_float(u0.x & 0xffff0000u);
    a[2] = __uint_as_float(u0.y << 16);
    a[3] = __uint_as_float(u0.y & 0xffff0000u);
    a[4] = __uint_as_float(u0.z << 16);
    a[5] = __uint_as_float(u0.z & 0xffff0000u);
    a[6] = __uint_as_float(u0.w << 16);
    a[7] = __uint_as_float(u0.w & 0xffff0000u);
    if (e >= end) return;
    int sidx = srt[e + q8];
    while (e < end) {
        int en = e + 8;
        int sn = 0;
        if (en < end) sn = srt[en + q8];          // prefetch next chunk's indices
        int s0 = BCAST8(sidx, 0);
        int s1 = BCAST8(sidx, 1);
        int s2 = BCAST8(sidx, 2);
        int s3 = BCAST8(sidx, 3);
        int s4 = BCAST8(sidx, 4);
        int s5 = BCAST8(sidx, 5);
        int s6 = BCAST8(sidx, 6);
        int s7 = BCAST8(sidx, 7);
        uint4 v0 = hb4[s0 * 8 + q8];
        uint4 v1 = hb4[s1 * 8 + q8];
        uint4 v2 = hb4[s2 * 8 + q8];
        uint4 v3 = hb4[s3 * 8 + q8];
        uint4 v4 = hb4[s4 * 8 + q8];
        uint4 v5 = hb4[s5 * 8 + q8];
        uint4 v6 = hb4[s6 * 8 + q8];
        uint4 v7 = hb4[s7 * 8 + q8];
        ACC8(v0); ACC8(v1); ACC8(v2); ACC8(v3);
        ACC8(v4); ACC8(v5); ACC8(v6); ACC8(v7);
        sidx = sn;
        e = en;
    }
}

// ---------------- gather core B: unscaled rows, applies dinv[src] (layer 1) --
// acc = di*h[node] + sum_j dinv[s_j] * h[s_j]
__device__ inline void gather8n(const int2* __restrict__ rs_pd,
                                const int* __restrict__ srt,
                                const uint4* __restrict__ hb4,
                                const float* __restrict__ dinv,
                                int node, int q8, float di, float a[8]) {
    int2 rp = rs_pd[node];
    int e = rp.x;
    int end = rp.x + rp.y;
    uint4 u0 = hb4[node * 8 + q8];   // self-loop term (unscaled)
    a[0] = di * __uint_as_float(u0.x << 16);
    a[1] = di * __uint_as_float(u0.x & 0xffff0000u);
    a[2] = di * __uint_as_float(u0.y << 16);
    a[3] = di * __uint_as_float(u0.y & 0xffff0000u);
    a[4] = di * __uint_as_float(u0.z << 16);
    a[5] = di * __uint_as_float(u0.z & 0xffff0000u);
    a[6] = di * __uint_as_float(u0.w << 16);
    a[7] = di * __uint_as_float(u0.w & 0xffff0000u);
    if (e >= end) return;
    int sidx = srt[e + q8];
    float dv = dinv[sidx];           // dinv[NN] = 0 covers pads
    while (e < end) {
        int en = e + 8;
        int sn = 0;
        float dn = 0.f;
        if (en < end) { sn = srt[en + q8]; dn = dinv[sn]; }   // prefetch
        int dvi = __float_as_int(dv);
        int s0 = BCAST8(sidx, 0);
        int s1 = BCAST8(sidx, 1);
        int s2 = BCAST8(sidx, 2);
        int s3 = BCAST8(sidx, 3);
        int s4 = BCAST8(sidx, 4);
        int s5 = BCAST8(sidx, 5);
        int s6 = BCAST8(sidx, 6);
        int s7 = BCAST8(sidx, 7);
        float w0 = __int_as_float(BCAST8(dvi, 0));
        float w1 = __int_as_float(BCAST8(dvi, 1));
        float w2 = __int_as_float(BCAST8(dvi, 2));
        float w3 = __int_as_float(BCAST8(dvi, 3));
        float w4 = __int_as_float(BCAST8(dvi, 4));
        float w5 = __int_as_float(BCAST8(dvi, 5));
        float w6 = __int_as_float(BCAST8(dvi, 6));
        float w7 = __int_as_float(BCAST8(dvi, 7));
        uint4 v0 = hb4[s0 * 8 + q8];
        uint4 v1 = hb4[s1 * 8 + q8];
        uint4 v2 = hb4[s2 * 8 + q8];
        uint4 v3 = hb4[s3 * 8 + q8];
        uint4 v4 = hb4[s4 * 8 + q8];
        uint4 v5 = hb4[s5 * 8 + q8];
        uint4 v6 = hb4[s6 * 8 + q8];
        uint4 v7 = hb4[s7 * 8 + q8];
        ACC8N(v0, w0); ACC8N(v1, w1); ACC8N(v2, w2); ACC8N(v3, w3);
        ACC8N(v4, w4); ACC8N(v5, w5); ACC8N(v6, w6); ACC8N(v7, w7);
        sidx = sn;
        dv = dn;
        e = en;
    }
}

// ---------------- K5: layer-1 aggregate -> LDS -> layer-2 gemm (MFMA) --------
__global__ void agg1_gemm2_kernel(const int2* __restrict__ rs_pd,
                                  const int* __restrict__ srt,
                                  const uint4* __restrict__ hb4,   // bufA (unscaled)
                                  const float* __restrict__ dinv,
                                  const float* __restrict__ b1,
                                  const unsigned short* __restrict__ Wp2,
                                  unsigned* __restrict__ out /* bufC bf16 rows */) {
    __shared__ unsigned short hsl[64][80];   // 10240 B, 16B-aligned rows
    int t = threadIdx.x;
    int lane = t & 63, wv = t >> 6;
    int node0 = blockIdx.x * 64;
    int q8 = lane & 7, g = lane >> 3;
    float4 bb0 = *(const float4*)(b1 + q8 * 8);
    float4 bb1 = *(const float4*)(b1 + q8 * 8 + 4);

    #pragma unroll
    for (int pass = 0; pass < 2; ++pass) {
        int nl = wv * 16 + pass * 8 + g;
        int node = node0 + nl;
        int cn = (node < NN) ? node : NN - 1;
        float di = dinv[cn];
        float a[8];
        gather8n(rs_pd, srt, hb4, dinv, cn, q8, di, a);
        a[0] = fmaxf(fmaf(di, a[0], bb0.x), 0.f);
        a[1] = fmaxf(fmaf(di, a[1], bb0.y), 0.f);
        a[2] = fmaxf(fmaf(di, a[2], bb0.z), 0.f);
        a[3] = fmaxf(fmaf(di, a[3], bb0.w), 0.f);
        a[4] = fmaxf(fmaf(di, a[4], bb1.x), 0.f);
        a[5] = fmaxf(fmaf(di, a[5], bb1.y), 0.f);
        a[6] = fmaxf(fmaf(di, a[6], bb1.z), 0.f);
        a[7] = fmaxf(fmaf(di, a[7], bb1.w), 0.f);
        uint4 pk;
        pk.x = f2bf(a[0]) | (f2bf(a[1]) << 16);
        pk.y = f2bf(a[2]) | (f2bf(a[3]) << 16);
        pk.z = f2bf(a[4]) | (f2bf(a[5]) << 16);
        pk.w = f2bf(a[6]) | (f2bf(a[7]) << 16);
        *(uint4*)&hsl[nl][q8 * 8] = pk;
    }
    __syncthreads();

    int m = lane & 15, quad = lane >> 4;
    Frag b[8];
    #pragma unroll
    for (int cs = 0; cs < 8; ++cs)
        b[cs].u = *(const uint4*)(Wp2 + ((cs * 4 + quad) * 16 + m) * 8);
    Frag a2[2];
    #pragma unroll
    for (int s = 0; s < 2; ++s)
        a2[s].u = *(const uint4*)&hsl[wv * 16 + m][s * 32 + quad * 8];

    v4f acc[4] = {};
    #pragma unroll
    for (int c = 0; c < 4; ++c) {
        acc[c] = __builtin_amdgcn_mfma_f32_16x16x32_bf16(a2[0].v, b[c * 2 + 0].v, acc[c], 0, 0, 0);
        acc[c] = __builtin_amdgcn_mfma_f32_16x16x32_bf16(a2[1].v, b[c * 2 + 1].v, acc[c], 0, 0, 0);
    }
    // bufC rows are PRE-scaled by dinv[onode] (layer-2 gather uses gather8)
    #pragma unroll
    for (int r = 0; r < 4; ++r) {
        int onode = node0 + wv * 16 + quad * 4 + r;
        float di = dinv[(onode < NN) ? onode : NN - 1];
        #pragma unroll
        for (int c = 0; c < 4; ++c) {
            float v = acc[c][r] * di;
            float p = __shfl_xor(v, 1);
            if (!(lane & 1)) {
                if (onode < NN)
                    out[onode * 32 + c * 8 + (m >> 1)] = f2bf(v) | (f2bf(p) << 16);
                else if (onode == NN)
                    out[onode * 32 + c * 8 + (m >> 1)] = 0u;   // zero row for padding
            }
        }
    }
}

// ---------------- K6: layer-2 aggregate fused with FC + log_softmax ----------
__global__ void aggregate2_final_kernel(const int2* __restrict__ rs_pd,
                                        const int* __restrict__ srt,
                                        const uint4* __restrict__ hb4,  // bufC
                                        const float* __restrict__ dinv,
                                        const float* __restrict__ b2,
                                        const float* __restrict__ Wfc,
                                        const float* __restrict__ bfc,
                                        float* __restrict__ out) {
    __shared__ float Ws[64][16];   // 4 KB
    __shared__ float hs[32][68];   // padded rows
    int t = threadIdx.x;
    #pragma unroll
    for (int k = 0; k < 4; ++k)
        ((float*)Ws)[k * 256 + t] = Wfc[k * 256 + t];

    int nl = t >> 3, q8 = t & 7;
    int node = blockIdx.x * 32 + nl;      // NN = 3125 * 32 exactly
    float a[8];
    gather8(rs_pd, srt, hb4, node, q8, a);
    float di = dinv[node];
    float4 bb0 = *(const float4*)(b2 + q8 * 8);
    float4 bb1 = *(const float4*)(b2 + q8 * 8 + 4);
    float4 r0, r1;
    r0.x = fmaxf(fmaf(di, a[0], bb0.x), 0.f);
    r0.y = fmaxf(fmaf(di, a[1], bb0.y), 0.f);
    r0.z = fmaxf(fmaf(di, a[2], bb0.z), 0.f);
    r0.w = fmaxf(fmaf(di, a[3], bb0.w), 0.f);
    r1.x = fmaxf(fmaf(di, a[4], bb1.x), 0.f);
    r1.y = fmaxf(fmaf(di, a[5], bb1.y), 0.f);
    r1.z = fmaxf(fmaf(di, a[6], bb1.z), 0.f);
    r1.w = fmaxf(fmaf(di, a[7], bb1.w), 0.f);
    *(float4*)&hs[nl][q8 * 8]     = r0;
    *(float4*)&hs[nl][q8 * 8 + 4] = r1;
    __syncthreads();

    #pragma unroll
    for (int it = 0; it < 2; ++it) {
        int idx = it * 256 + t;
        int n2 = idx >> 4;
        int c  = idx & 15;
        float acc = bfc[c];
        #pragma unroll
        for (int k = 0; k < 64; ++k)
            acc = fmaf(hs[n2][k], Ws[k][c], acc);
        float mx = acc;
        #pragma unroll
        for (int off = 8; off; off >>= 1)
            mx = fmaxf(mx, __shfl_xor(mx, off, 16));
        float ex = __expf(acc - mx);
        float s = ex;
        #pragma unroll
        for (int off = 8; off; off >>= 1)
            s += __shfl_xor(s, off, 16);
        out[blockIdx.x * 512 + idx] = acc - mx - __logf(s);
    }
}

extern "C" void kernel_launch(void* const* d_in, const int* in_sizes, int n_in,
                              void* d_out, int out_size, void* d_ws, size_t ws_size,
                              hipStream_t stream) {
    const float* x   = (const float*)d_in[0];
    const int*   ei  = (const int*)d_in[1];     // [2, E] int32
    const float* W1  = (const float*)d_in[2];
    const float* b1  = (const float*)d_in[3];
    const float* W2  = (const float*)d_in[4];
    const float* b2  = (const float*)d_in[5];
    const float* Wfc = (const float*)d_in[6];
    const float* bfc = (const float*)d_in[7];
    float* out = (float*)d_out;

    char* ws = (char*)d_ws;
    int2*     rs_pd  = (int2*)(ws + 0);             //  800,000 B
    float*    dinv   = (float*)(ws + 800000);       //  (NN+1)*4 -> ends 1200004
    int*      btot   = (int*)(ws + 1200128);        //  3128 B -> ends 1203256
    int*      histT  = (int*)(ws + 1203328);        //  1,601,536 -> ends 2804864
    int*      baseT  = (int*)(ws + 2804864);        //  1,601,536 -> ends 4406400
    int*      srt    = (int*)(ws + 4406400);        //  9,202,688 -> ends 13609088
    unsigned* bufA   = (unsigned*)(ws + 13609088);  // 12,800,128 -> ends 26409216
    int*      pairs  = (int*)(ws + 26409216);       //  6.4 MB (dead after K4)
    unsigned* bufC   = (unsigned*)(ws + 26409216);  // 12,800,128, overlays pairs -> ends 39209344
    unsigned short* Wp1 = (unsigned short*)(ws + 39209344);  // 8 KB
    unsigned short* Wp2 = (unsigned short*)(ws + 39217536);  // 8 KB (ends 39225728)

    const int* src = ei;        // edge_index[0]
    const int* dst = ei + NE;   // edge_index[1]

    // K1: histogram + weight pack
    hist_wpack_kernel<<<NSB + 2, 256, 0, stream>>>(dst, histT, W1, W2, Wp1, Wp2);
    // K2: per-bucket column scan
    colscan_kernel<<<NBUCK, 256, 0, stream>>>(histT, baseT, btot);
    // K3: bucket scatter + layer-1 GEMM (independent halves, one dispatch)
    scatter_gemm_kernel<<<NSB + GEMMB, 256, 0, stream>>>(src, dst, baseT, btot, pairs,
                                                         x, Wp1, bufA);
    // K4: padded CSR placement + deg/dinv
    place_deg_kernel<<<NBUCK, 256, 0, stream>>>(btot, pairs, rs_pd, dinv, srt);
    // K5: layer-1 aggregate (dinv at gather) + layer-2 gemm
    agg1_gemm2_kernel<<<(NN + 63) / 64, 256, 0, stream>>>(rs_pd, srt,
        (const uint4*)bufA, dinv, b1, Wp2, bufC);
    // K6: layer-2 aggregate + FC + log_softmax
    aggregate2_final_kernel<<<NN / 32, 256, 0, stream>>>(rs_pd, srt,
        (const uint4*)bufC, dinv, b2, Wfc, bfc, out);
}